// Round 1
// baseline (410.319 us; speedup 1.0000x reference)
//
#include <hip/hip_runtime.h>

#define BS 4096
#define IN_DIM 2048
#define NFFT 16384
#define TOTAL_D 129
#define SLACK 64
#define KF 128          // GEMM feature count (DC handled separately)
#define NPROJ 160       // padded proj cols (129 -> 160 = 10 n-tiles)
#define SPLITK 8

#define INV_N_SQRT 0.0078125f            // 1/128
#define SC_PAIR 0.011048543456039804f    // sqrt(2)/128
#define TWO_PI_OVER_N 3.8349519697141029e-4f

typedef __attribute__((ext_vector_type(8))) short bf16x8;
typedef __attribute__((ext_vector_type(4))) float f32x4;

__device__ __forceinline__ ushort f2bf(float f) {
    union { float f; unsigned u; } v; v.f = f;
    unsigned r = v.u + 0x7fffu + ((v.u >> 16) & 1u);   // round-nearest-even
    return (ushort)(r >> 16);
}

// ---------------------------------------------------------------------------
// Basis: Bb[t][k] bf16, k in [0,128). k<64: pure cos/sin of f=k/2+1 (exact
// integer phase); k>=64: Ws[t][k-64]. Scales folded into hs features.
// ---------------------------------------------------------------------------
__global__ __launch_bounds__(256) void k_basis(const float* __restrict__ Ws,
                                               ushort* __restrict__ Bb) {
    int idx = blockIdx.x * 256 + threadIdx.x;    // 16384*16 work items
    int t = idx >> 4, g = idx & 15;
    ushort r[8];
    if (g < 8) {
#pragma unroll
        for (int p = 0; p < 4; ++p) {
            int f = 4 * g + p + 1;                       // 1..32
            int phase = (f * t) & (NFFT - 1);
            float ang = (float)phase * TWO_PI_OVER_N;
            float sv, cv;
            __sincosf(ang, &sv, &cv);
            r[2 * p] = f2bf(cv);
            r[2 * p + 1] = f2bf(sv);
        }
    } else {
        const float* w = &Ws[(size_t)t * SLACK + (g - 8) * 8];
        float4 w0 = *(const float4*)w;
        float4 w1 = *(const float4*)(w + 4);
        r[0] = f2bf(w0.x); r[1] = f2bf(w0.y); r[2] = f2bf(w0.z); r[3] = f2bf(w0.w);
        r[4] = f2bf(w1.x); r[5] = f2bf(w1.y); r[6] = f2bf(w1.z); r[7] = f2bf(w1.w);
    }
    ushort4 lo = {r[0], r[1], r[2], r[3]};
    ushort4 hi = {r[4], r[5], r[6], r[7]};
    ushort* dst = &Bb[(size_t)t * KF + g * 8];
    *(ushort4*)dst = lo;
    *(ushort4*)(dst + 4) = hi;
}

// ---------------------------------------------------------------------------
// Proj GEMM: h_part[kz][b][c] = sum_{k in split kz} x[b][k] * W[min(c,128)][k]
// bf16 MFMA 16x16x32, tile 128x160, 4 waves of 64x80 (4x5 frags), BK=32.
// SPLITK=8 -> 256 blocks = full CU coverage.
// ---------------------------------------------------------------------------
__global__ __launch_bounds__(256, 2) void k_proj(const float* __restrict__ x,
                                                 const float* __restrict__ W,
                                                 float* __restrict__ hp) {
    __shared__ ushort As[128 * 40];   // stride 40 bf16 = 20 words: <=2-way banks
    __shared__ ushort Bs[160 * 40];
    const int tid = threadIdx.x;
    const int lane = tid & 63, wave = tid >> 6;
    const int quad = lane >> 4, m = lane & 15;
    const int wm = wave & 1, wn = wave >> 1;
    const int r0 = blockIdx.x * 128;
    const int kbase = blockIdx.y * (IN_DIM / SPLITK);

    f32x4 acc[4][5];
#pragma unroll
    for (int i = 0; i < 4; ++i)
#pragma unroll
        for (int j = 0; j < 5; ++j) acc[i][j] = 0.f;

    for (int ch = 0; ch < IN_DIM / SPLITK / 32; ++ch) {
        const int kb = kbase + ch * 32;
        // stage x tile 128x32 (fp32 -> bf16)
#pragma unroll
        for (int it = 0; it < 4; ++it) {
            int v = tid + it * 256;
            int row = v >> 3, c = v & 7;
            float4 xv = *(const float4*)&x[(size_t)(r0 + row) * IN_DIM + kb + c * 4];
            ushort4 o = {f2bf(xv.x), f2bf(xv.y), f2bf(xv.z), f2bf(xv.w)};
            *(ushort4*)&As[row * 40 + c * 4] = o;
        }
        // stage W tile 160x32 (rows >=129 clamped; results discarded later)
#pragma unroll
        for (int it = 0; it < 5; ++it) {
            int v = tid + it * 256;
            int row = v >> 3, c = v & 7;
            int rw = row < TOTAL_D ? row : TOTAL_D - 1;
            float4 wv = *(const float4*)&W[(size_t)rw * IN_DIM + kb + c * 4];
            ushort4 o = {f2bf(wv.x), f2bf(wv.y), f2bf(wv.z), f2bf(wv.w)};
            *(ushort4*)&Bs[row * 40 + c * 4] = o;
        }
        __syncthreads();
        bf16x8 af[4], bfr[5];
#pragma unroll
        for (int i = 0; i < 4; ++i)
            af[i] = *(const bf16x8*)&As[(wm * 64 + i * 16 + m) * 40 + quad * 8];
#pragma unroll
        for (int j = 0; j < 5; ++j)
            bfr[j] = *(const bf16x8*)&Bs[(wn * 80 + j * 16 + m) * 40 + quad * 8];
#pragma unroll
        for (int i = 0; i < 4; ++i)
#pragma unroll
            for (int j = 0; j < 5; ++j)
                acc[i][j] = __builtin_amdgcn_mfma_f32_16x16x32_bf16(af[i], bfr[j], acc[i][j], 0, 0, 0);
        __syncthreads();
    }
    // epilogue: C/D layout col=lane&15, row=quad*4+reg
#pragma unroll
    for (int i = 0; i < 4; ++i)
#pragma unroll
        for (int reg = 0; reg < 4; ++reg) {
            int row = r0 + wm * 64 + i * 16 + quad * 4 + reg;
            float* orow = &hp[((size_t)blockIdx.y * BS + row) * NPROJ + wn * 80 + m];
#pragma unroll
            for (int j = 0; j < 5; ++j) orow[j * 16] = acc[i][j][reg];
        }
}

// ---------------------------------------------------------------------------
// Finalize: sum split-K partials + bias -> dc0 (fp32, pre-scaled by 1/128)
// and scaled bf16 features hs[b][k]  (k<64: *sqrt2/128 ; k>=64: slack as-is)
// ---------------------------------------------------------------------------
__global__ __launch_bounds__(256) void k_finalize(const float* __restrict__ hp,
                                                  const float* __restrict__ bvec,
                                                  float* __restrict__ dc0,
                                                  ushort* __restrict__ hs) {
    int b = blockIdx.x * 256 + threadIdx.x;   // 0..4095
    int g = blockIdx.y;                       // 0..16 (cols 8g..8g+7, used c<=128)
    int c0 = g * 8;
    float v[8];
#pragma unroll
    for (int e = 0; e < 8; ++e) v[e] = 0.f;
#pragma unroll
    for (int s = 0; s < SPLITK; ++s) {
        const float* p = &hp[((size_t)s * BS + b) * NPROJ + c0];
        float4 p0 = *(const float4*)p;
        float4 p1 = *(const float4*)(p + 4);
        v[0] += p0.x; v[1] += p0.y; v[2] += p0.z; v[3] += p0.w;
        v[4] += p1.x; v[5] += p1.y; v[6] += p1.z; v[7] += p1.w;
    }
#pragma unroll
    for (int e = 0; e < 8; ++e) {
        int c = c0 + e;
        if (c >= TOTAL_D) break;
        float val = v[e] + bvec[c];
        if (c == 0) {
            dc0[b] = val * INV_N_SQRT;
        } else {
            int k = c - 1;
            float sc = (k < 64) ? SC_PAIR : 1.f;
            hs[(size_t)b * KF + k] = f2bf(val * sc);
        }
    }
}

// ---------------------------------------------------------------------------
// Main GEMM: out[b][t] = dc0[b] + sum_k hs[b][k]*Bb[t][k]
// LDS-FREE: Bb (4 MB) and hs (1 MB) are L2-resident; the [row][k] bf16 layout
// IS the MFMA fragment layout (lane row = &15, quad = 16B k-granule), so each
// fragment is one global_load_dwordx4 straight to VGPR. No LDS, no barriers,
// 4 blocks/CU. XCD-chunked swizzle (by-fastest) keeps each XCD's working set
// at 512 KB Bb + 1 MB hs (L2-fit); non-temporal out stores keep the 268 MB
// write stream from evicting the operands.
// OPERAND-SWAPPED: MFMA-M = t, MFMA-N = b; each acc f32x4 is a direct
// dwordx4 store, 4 quads of a quarter-wave complete a 64B line.
// ---------------------------------------------------------------------------
__global__ __launch_bounds__(256, 4) void k_main(const ushort* __restrict__ hs,
                                                 const float* __restrict__ dc0,
                                                 const ushort* __restrict__ Bb,
                                                 float* __restrict__ out) {
    const int tid = threadIdx.x;
    const int lane = tid & 63, wave = tid >> 6;
    const int quad = lane >> 4, m = lane & 15;
    const int wm = wave & 1, wn = wave >> 1;   // wm -> t-half, wn -> b-half

    // XCD-chunked bijective swizzle (4096 % 8 == 0): XCD k owns wgid
    // [k*512, (k+1)*512). by-fastest decomposition -> each XCD sees 16
    // t-tiles x all 32 b-tiles: working set 512KB Bb + 1MB hs per L2.
    int orig = blockIdx.x;                       // 0..4095
    int wgid = ((orig & 7) << 9) + (orig >> 3);
    int tx = wgid >> 5, by = wgid & 31;
    const int t0 = tx * 128;
    const int b0 = by * 128;

    // per-lane fragment base pointers (16B per quad, row = m)
    const ushort* pA = Bb + (((size_t)(t0 + wm * 64 + m)) << 7) + quad * 8;
    const ushort* pB = hs + (((size_t)(b0 + wn * 64 + m)) << 7) + quad * 8;

    // DC term as C-init: per-lane scalar broadcast of dc0[b]
    f32x4 acc[4][4];
#pragma unroll
    for (int j = 0; j < 4; ++j) {
        float d = dc0[b0 + wn * 64 + j * 16 + m];
#pragma unroll
        for (int i = 0; i < 4; ++i) acc[i][j] = d;
    }

#pragma unroll
    for (int ks = 0; ks < 4; ++ks) {
        bf16x8 af[4], bfr[4];
#pragma unroll
        for (int i = 0; i < 4; ++i)
            af[i] = *(const bf16x8*)(pA + (size_t)i * 16 * KF + ks * 32);
#pragma unroll
        for (int j = 0; j < 4; ++j)
            bfr[j] = *(const bf16x8*)(pB + (size_t)j * 16 * KF + ks * 32);
#pragma unroll
        for (int i = 0; i < 4; ++i)
#pragma unroll
            for (int j = 0; j < 4; ++j)
                acc[i][j] = __builtin_amdgcn_mfma_f32_16x16x32_bf16(af[i], bfr[j], acc[i][j], 0, 0, 0);
    }

    // epilogue: 16 NT dwordx4 stores per thread, quads complete 64B lines
#pragma unroll
    for (int j = 0; j < 4; ++j) {
        size_t rowb = (size_t)(b0 + wn * 64 + j * 16 + m);
        float* orow = out + rowb * NFFT + t0 + wm * 64 + quad * 4;
#pragma unroll
        for (int i = 0; i < 4; ++i)
            __builtin_nontemporal_store(acc[i][j], (f32x4*)&orow[i * 16]);
    }
}

extern "C" void kernel_launch(void* const* d_in, const int* in_sizes, int n_in,
                              void* d_out, int out_size, void* d_ws, size_t ws_size,
                              hipStream_t stream) {
    const float* x   = (const float*)d_in[0];
    const float* W   = (const float*)d_in[1];
    const float* b   = (const float*)d_in[2];
    const float* Wsl = (const float*)d_in[3];
    float* out = (float*)d_out;

    char* ws = (char*)d_ws;
    float*  h_part = (float*)ws;                        // 8*4096*160*4 = 21.0 MB
    ushort* Bb     = (ushort*)(ws + 20971520);          // 16384*128*2  =  4.0 MB
    ushort* hs     = (ushort*)(ws + 25165824);          // 4096*128*2   =  1.0 MB
    float*  dc0    = (float*)(ws + 26214400);           // 4096*4       = 16 KB

    k_basis<<<NFFT * 16 / 256, 256, 0, stream>>>(Wsl, Bb);
    k_proj<<<dim3(BS / 128, SPLITK), 256, 0, stream>>>(x, W, h_part);
    k_finalize<<<dim3(BS / 256, 17), 256, 0, stream>>>(h_part, b, dc0, hs);
    k_main<<<NFFT / 128 * (BS / 128), 256, 0, stream>>>(hs, dc0, Bb, out);
}

// Round 2
// 375.172 us; speedup vs baseline: 1.0937x; 1.0937x over previous
//
#include <hip/hip_runtime.h>

#define BS 4096
#define IN_DIM 2048
#define NFFT 16384
#define TOTAL_D 129
#define SLACK 64
#define KF 128          // GEMM feature count (DC handled separately)
#define NPROJ 160       // padded proj cols (129 -> 160 = 10 n-tiles)
#define SPLITK 8

#define INV_N_SQRT 0.0078125f            // 1/128
#define SC_PAIR 0.011048543456039804f    // sqrt(2)/128
#define TWO_PI_OVER_N 3.8349519697141029e-4f

typedef __attribute__((ext_vector_type(8))) short bf16x8;
typedef __attribute__((ext_vector_type(4))) float f32x4;

__device__ __forceinline__ ushort f2bf(float f) {
    union { float f; unsigned u; } v; v.f = f;
    unsigned r = v.u + 0x7fffu + ((v.u >> 16) & 1u);   // round-nearest-even
    return (ushort)(r >> 16);
}

// ---------------------------------------------------------------------------
// Basis: Bb[t][k] bf16, k in [0,128). k<64: pure cos/sin of f=k/2+1 (exact
// integer phase); k>=64: Ws[t][k-64]. Scales folded into hs features.
// ---------------------------------------------------------------------------
__global__ __launch_bounds__(256) void k_basis(const float* __restrict__ Ws,
                                               ushort* __restrict__ Bb) {
    int idx = blockIdx.x * 256 + threadIdx.x;    // 16384*16 work items
    int t = idx >> 4, g = idx & 15;
    ushort r[8];
    if (g < 8) {
#pragma unroll
        for (int p = 0; p < 4; ++p) {
            int f = 4 * g + p + 1;                       // 1..32
            int phase = (f * t) & (NFFT - 1);
            float ang = (float)phase * TWO_PI_OVER_N;
            float sv, cv;
            __sincosf(ang, &sv, &cv);
            r[2 * p] = f2bf(cv);
            r[2 * p + 1] = f2bf(sv);
        }
    } else {
        const float* w = &Ws[(size_t)t * SLACK + (g - 8) * 8];
        float4 w0 = *(const float4*)w;
        float4 w1 = *(const float4*)(w + 4);
        r[0] = f2bf(w0.x); r[1] = f2bf(w0.y); r[2] = f2bf(w0.z); r[3] = f2bf(w0.w);
        r[4] = f2bf(w1.x); r[5] = f2bf(w1.y); r[6] = f2bf(w1.z); r[7] = f2bf(w1.w);
    }
    ushort4 lo = {r[0], r[1], r[2], r[3]};
    ushort4 hi = {r[4], r[5], r[6], r[7]};
    ushort* dst = &Bb[(size_t)t * KF + g * 8];
    *(ushort4*)dst = lo;
    *(ushort4*)(dst + 4) = hi;
}

// ---------------------------------------------------------------------------
// Proj GEMM: h_part[kz][b][c] = sum_{k in split kz} x[b][k] * W[min(c,128)][k]
// bf16 MFMA 16x16x32, tile 128x160, 4 waves of 64x80 (4x5 frags), BK=32.
// SPLITK=8 -> 256 blocks = full CU coverage.
// ---------------------------------------------------------------------------
__global__ __launch_bounds__(256, 2) void k_proj(const float* __restrict__ x,
                                                 const float* __restrict__ W,
                                                 float* __restrict__ hp) {
    __shared__ ushort As[128 * 40];   // stride 40 bf16 = 20 words: <=2-way banks
    __shared__ ushort Bs[160 * 40];
    const int tid = threadIdx.x;
    const int lane = tid & 63, wave = tid >> 6;
    const int quad = lane >> 4, m = lane & 15;
    const int wm = wave & 1, wn = wave >> 1;
    const int r0 = blockIdx.x * 128;
    const int kbase = blockIdx.y * (IN_DIM / SPLITK);

    f32x4 acc[4][5];
#pragma unroll
    for (int i = 0; i < 4; ++i)
#pragma unroll
        for (int j = 0; j < 5; ++j) acc[i][j] = 0.f;

    for (int ch = 0; ch < IN_DIM / SPLITK / 32; ++ch) {
        const int kb = kbase + ch * 32;
        // stage x tile 128x32 (fp32 -> bf16)
#pragma unroll
        for (int it = 0; it < 4; ++it) {
            int v = tid + it * 256;
            int row = v >> 3, c = v & 7;
            float4 xv = *(const float4*)&x[(size_t)(r0 + row) * IN_DIM + kb + c * 4];
            ushort4 o = {f2bf(xv.x), f2bf(xv.y), f2bf(xv.z), f2bf(xv.w)};
            *(ushort4*)&As[row * 40 + c * 4] = o;
        }
        // stage W tile 160x32 (rows >=129 clamped; results discarded later)
#pragma unroll
        for (int it = 0; it < 5; ++it) {
            int v = tid + it * 256;
            int row = v >> 3, c = v & 7;
            int rw = row < TOTAL_D ? row : TOTAL_D - 1;
            float4 wv = *(const float4*)&W[(size_t)rw * IN_DIM + kb + c * 4];
            ushort4 o = {f2bf(wv.x), f2bf(wv.y), f2bf(wv.z), f2bf(wv.w)};
            *(ushort4*)&Bs[row * 40 + c * 4] = o;
        }
        __syncthreads();
        bf16x8 af[4], bfr[5];
#pragma unroll
        for (int i = 0; i < 4; ++i)
            af[i] = *(const bf16x8*)&As[(wm * 64 + i * 16 + m) * 40 + quad * 8];
#pragma unroll
        for (int j = 0; j < 5; ++j)
            bfr[j] = *(const bf16x8*)&Bs[(wn * 80 + j * 16 + m) * 40 + quad * 8];
#pragma unroll
        for (int i = 0; i < 4; ++i)
#pragma unroll
            for (int j = 0; j < 5; ++j)
                acc[i][j] = __builtin_amdgcn_mfma_f32_16x16x32_bf16(af[i], bfr[j], acc[i][j], 0, 0, 0);
        __syncthreads();
    }
    // epilogue: C/D layout col=lane&15, row=quad*4+reg
#pragma unroll
    for (int i = 0; i < 4; ++i)
#pragma unroll
        for (int reg = 0; reg < 4; ++reg) {
            int row = r0 + wm * 64 + i * 16 + quad * 4 + reg;
            float* orow = &hp[((size_t)blockIdx.y * BS + row) * NPROJ + wn * 80 + m];
#pragma unroll
            for (int j = 0; j < 5; ++j) orow[j * 16] = acc[i][j][reg];
        }
}

// ---------------------------------------------------------------------------
// Finalize: sum split-K partials + bias -> dc0 (fp32, pre-scaled by 1/128)
// and scaled bf16 features hs[b][k]  (k<64: *sqrt2/128 ; k>=64: slack as-is)
// ---------------------------------------------------------------------------
__global__ __launch_bounds__(256) void k_finalize(const float* __restrict__ hp,
                                                  const float* __restrict__ bvec,
                                                  float* __restrict__ dc0,
                                                  ushort* __restrict__ hs) {
    int b = blockIdx.x * 256 + threadIdx.x;   // 0..4095
    int g = blockIdx.y;                       // 0..16 (cols 8g..8g+7, used c<=128)
    int c0 = g * 8;
    float v[8];
#pragma unroll
    for (int e = 0; e < 8; ++e) v[e] = 0.f;
#pragma unroll
    for (int s = 0; s < SPLITK; ++s) {
        const float* p = &hp[((size_t)s * BS + b) * NPROJ + c0];
        float4 p0 = *(const float4*)p;
        float4 p1 = *(const float4*)(p + 4);
        v[0] += p0.x; v[1] += p0.y; v[2] += p0.z; v[3] += p0.w;
        v[4] += p1.x; v[5] += p1.y; v[6] += p1.z; v[7] += p1.w;
    }
#pragma unroll
    for (int e = 0; e < 8; ++e) {
        int c = c0 + e;
        if (c >= TOTAL_D) break;
        float val = v[e] + bvec[c];
        if (c == 0) {
            dc0[b] = val * INV_N_SQRT;
        } else {
            int k = c - 1;
            float sc = (k < 64) ? SC_PAIR : 1.f;
            hs[(size_t)b * KF + k] = f2bf(val * sc);
        }
    }
}

// ---------------------------------------------------------------------------
// Main GEMM: out[b][t] = dc0[b] + sum_k hs[b][k]*Bb[t][k]
// LDS-staged (r0 structure, proven) + TWO-PHASE K-PIPELINE (T14 issue-early /
// write-late): all 16 staging loads issued up front into VGPRs; half0 (k<64)
// written+barriered first; ks=0,1 MFMAs run while half1's loads drain in
// flight; then half1 ds_write -> barrier -> ks=2,3. XOR swizzle granules 0-7 /
// 8-15 are closed under ^(row&7), so each ks-pair touches only its half.
// OPERAND-SWAPPED: MFMA-M = t, MFMA-N = b; each acc f32x4 is a direct
// dwordx4 store, 4 quads of a quarter-wave complete a 64B line.
// ---------------------------------------------------------------------------
__global__ __launch_bounds__(256, 2) void k_main(const ushort* __restrict__ hs,
                                                 const float* __restrict__ dc0,
                                                 const ushort* __restrict__ Bb,
                                                 float* __restrict__ out) {
    __shared__ ushort As[128 * 128];   // basis tile [t_local][k], swizzled
    __shared__ ushort Bs[128 * 128];   // hs tile    [b_local][k], swizzled
    const int tid = threadIdx.x;
    const int lane = tid & 63, wave = tid >> 6;
    const int quad = lane >> 4, m = lane & 15;
    const int wm = wave & 1, wn = wave >> 1;   // wm -> t-half, wn -> b-half
    const int t0 = blockIdx.x * 128;
    const int b0 = blockIdx.y * 128;

    // staging coords: per half, each thread covers 4 rows x one 16B granule
    const int srow = tid >> 3;    // 0..31
    const int sg   = tid & 7;     // granule within k-half (16B = 8 bf16)

    // issue ALL staging loads up front (in-order vmcnt => counted waits later)
    uint4 ra0[4], rb0[4], ra1[4], rb1[4];
#pragma unroll
    for (int it = 0; it < 4; ++it) {
        int row = srow + it * 32;
        ra0[it] = *(const uint4*)&Bb[((size_t)(t0 + row) << 7) + sg * 8];
        rb0[it] = *(const uint4*)&hs[((size_t)(b0 + row) << 7) + sg * 8];
    }
#pragma unroll
    for (int it = 0; it < 4; ++it) {
        int row = srow + it * 32;
        ra1[it] = *(const uint4*)&Bb[((size_t)(t0 + row) << 7) + (8 + sg) * 8];
        rb1[it] = *(const uint4*)&hs[((size_t)(b0 + row) << 7) + (8 + sg) * 8];
    }

    // write half0 into LDS (waits only on the first 8 loads; half1 in flight)
#pragma unroll
    for (int it = 0; it < 4; ++it) {
        int row = srow + it * 32;
        *(uint4*)&As[(row << 7) + ((sg ^ (row & 7)) * 8)] = ra0[it];
        *(uint4*)&Bs[(row << 7) + ((sg ^ (row & 7)) * 8)] = rb0[it];
    }

    // DC term as C-init: per-lane scalar broadcast of dc0[b]
    f32x4 acc[4][4];
#pragma unroll
    for (int j = 0; j < 4; ++j) {
        float d = dc0[b0 + wn * 64 + j * 16 + m];
#pragma unroll
        for (int i = 0; i < 4; ++i) acc[i][j] = d;
    }
    __syncthreads();

    // compute ks = 0,1 from half0 while half1's global loads drain
#pragma unroll
    for (int ks = 0; ks < 2; ++ks) {
        bf16x8 af[4], bfr[4];
#pragma unroll
        for (int i = 0; i < 4; ++i) {
            int row = wm * 64 + i * 16 + m;
            af[i] = *(const bf16x8*)&As[(row << 7) + (((ks * 4 + quad) ^ (row & 7)) * 8)];
        }
#pragma unroll
        for (int j = 0; j < 4; ++j) {
            int row = wn * 64 + j * 16 + m;
            bfr[j] = *(const bf16x8*)&Bs[(row << 7) + (((ks * 4 + quad) ^ (row & 7)) * 8)];
        }
#pragma unroll
        for (int i = 0; i < 4; ++i)
#pragma unroll
            for (int j = 0; j < 4; ++j)
                acc[i][j] = __builtin_amdgcn_mfma_f32_16x16x32_bf16(af[i], bfr[j], acc[i][j], 0, 0, 0);
    }
    // keep half1's ds_writes (and their vmcnt wait) BELOW the MFMAs above
    __builtin_amdgcn_sched_barrier(0);

    // write half1 into LDS (disjoint granules 8..15; no race with half0 reads)
#pragma unroll
    for (int it = 0; it < 4; ++it) {
        int row = srow + it * 32;
        *(uint4*)&As[(row << 7) + (((8 + sg) ^ (row & 7)) * 8)] = ra1[it];
        *(uint4*)&Bs[(row << 7) + (((8 + sg) ^ (row & 7)) * 8)] = rb1[it];
    }
    __syncthreads();

    // compute ks = 2,3 from half1
#pragma unroll
    for (int ks = 2; ks < 4; ++ks) {
        bf16x8 af[4], bfr[4];
#pragma unroll
        for (int i = 0; i < 4; ++i) {
            int row = wm * 64 + i * 16 + m;
            af[i] = *(const bf16x8*)&As[(row << 7) + (((ks * 4 + quad) ^ (row & 7)) * 8)];
        }
#pragma unroll
        for (int j = 0; j < 4; ++j) {
            int row = wn * 64 + j * 16 + m;
            bfr[j] = *(const bf16x8*)&Bs[(row << 7) + (((ks * 4 + quad) ^ (row & 7)) * 8)];
        }
#pragma unroll
        for (int i = 0; i < 4; ++i)
#pragma unroll
            for (int j = 0; j < 4; ++j)
                acc[i][j] = __builtin_amdgcn_mfma_f32_16x16x32_bf16(af[i], bfr[j], acc[i][j], 0, 0, 0);
    }

    // epilogue: 16 dwordx4 stores per thread, quads complete 64B lines
#pragma unroll
    for (int j = 0; j < 4; ++j) {
        size_t rowb = (size_t)(b0 + wn * 64 + j * 16 + m);
        float* orow = out + rowb * NFFT + t0 + wm * 64 + quad * 4;
#pragma unroll
        for (int i = 0; i < 4; ++i)
            *(f32x4*)&orow[i * 16] = acc[i][j];
    }
}

extern "C" void kernel_launch(void* const* d_in, const int* in_sizes, int n_in,
                              void* d_out, int out_size, void* d_ws, size_t ws_size,
                              hipStream_t stream) {
    const float* x   = (const float*)d_in[0];
    const float* W   = (const float*)d_in[1];
    const float* b   = (const float*)d_in[2];
    const float* Wsl = (const float*)d_in[3];
    float* out = (float*)d_out;

    char* ws = (char*)d_ws;
    float*  h_part = (float*)ws;                        // 8*4096*160*4 = 21.0 MB
    ushort* Bb     = (ushort*)(ws + 20971520);          // 16384*128*2  =  4.0 MB
    ushort* hs     = (ushort*)(ws + 25165824);          // 4096*128*2   =  1.0 MB
    float*  dc0    = (float*)(ws + 26214400);           // 4096*4       = 16 KB

    k_basis<<<NFFT * 16 / 256, 256, 0, stream>>>(Wsl, Bb);
    k_proj<<<dim3(BS / 128, SPLITK), 256, 0, stream>>>(x, W, h_part);
    k_finalize<<<dim3(BS / 256, 17), 256, 0, stream>>>(h_part, b, dc0, hs);
    k_main<<<dim3(NFFT / 128, BS / 128), 256, 0, stream>>>(hs, dc0, Bb, out);
}